// Round 6
// baseline (193.767 us; speedup 1.0000x reference)
//
#include <hip/hip_runtime.h>

#define T_STEPS 256
#define IMG 512
#define HW (IMG * IMG)
#define TW 32
#define TH 8
#define HTW 40                 // halo row floats: cols -4..35, all 16B chunks
#define HTH 12                 // halo rows -2..9
#define HCHUNK (HTH * 10)      // 120 16B chunks
#define BUF_FLOATS 512         // padded to 128 chunks = 2 global_load_lds issues

// Zero page for fully-OOB halo chunks (device globals: never written, stays 0).
__device__ __align__(16) float g_zeropage[8] = {0, 0, 0, 0, 0, 0, 0, 0};

typedef const __attribute__((address_space(1))) unsigned int* gptr_t;
typedef __attribute__((address_space(3))) unsigned int* lptr_t;
typedef float vf4 __attribute__((ext_vector_type(4)));   // native vec for nt-store

// out[t] = 0.8*out[t-1] + conv(x)[t-1]; out[0]=0 — conv and LI scan commute.
// Single-wave blocks (no barriers). Staging via global_load_lds DMA (no
// ds_writes, no staging VGPRs): ring-4 LDS buffers, stage distance 3, counted
// asm vmcnt (never 0) keeps 3 frames of loads in flight across steps.
__launch_bounds__(64)
__global__ void conv_li_kernel(const float* __restrict__ x,
                               const float* __restrict__ kern,
                               float* __restrict__ out) {
    __shared__ __align__(16) float lds[4][BUF_FLOATS];
    const int tid = threadIdx.x;
    const int bid = blockIdx.x;
    // 1024 blocks over 8 XCDs (bijective): vertical halo sharing stays per-XCD L2.
    const int vbid = (bid & 7) * 128 + (bid >> 3);
    const int bx = vbid & 15;      // 16 tiles across
    const int by = vbid >> 4;      // 64 tile rows

    // 5x5 kernel -> wave-uniform (SGPR) weights.
    float kw[25];
#pragma unroll
    for (int i = 0; i < 25; ++i)
        kw[i] = __int_as_float(__builtin_amdgcn_readfirstlane(__float_as_int(kern[i])));

    // Per-lane DMA source chunks: chunk tid (issue A) and tid+64 (issue B).
    // Chunk c -> halo row c/10, col-chunk c%10; gx = bx*32-4+4*cc is 16B-aligned
    // and every chunk is fully in-bounds or fully out (-> zero page).
    const float* srcA; const float* srcB; bool okA, okB;
    {
        int c = tid;
        int row = c / 10, cc = c - row * 10;
        int gy = by * TH + row - 2, gx = bx * TW + cc * 4 - 4;
        okA = (gy >= 0) && (gy < IMG) && (gx >= 0) && (gx <= IMG - 4);
        srcA = x + (size_t)(okA ? gy : 0) * IMG + (okA ? gx : 0);
        c = tid + 64;
        row = c / 10; cc = c - row * 10;
        gy = by * TH + row - 2; gx = bx * TW + cc * 4 - 4;
        okB = (c < HCHUNK) && (gy >= 0) && (gy < IMG) && (gx >= 0) && (gx <= IMG - 4);
        srcB = x + (size_t)(okB ? gy : 0) * IMG + (okB ? gx : 0);
    }

    auto GLDS = [&](float* ldsbase, int tf) {
        const float* pA = okA ? srcA + (size_t)tf * HW : g_zeropage;
        const float* pB = okB ? srcB + (size_t)tf * HW : g_zeropage;
        __builtin_amdgcn_global_load_lds((gptr_t)pA, (lptr_t)(ldsbase), 16, 0, 0);
        __builtin_amdgcn_global_load_lds((gptr_t)pB, (lptr_t)(ldsbase + 256), 16, 0, 0);
    };

    const int q = tid & 7;         // col-quad (4 out cols each)
    const int rr = tid >> 3;       // out row within tile
    const int roff = rr * HTW + q * 4 + 2;   // halo dword of (out col q*4) - 2
    const size_t obase = (size_t)(by * TH + rr) * IMG + bx * TW + q * 4;

    vf4 st = {0.f, 0.f, 0.f, 0.f};

    auto STEP = [&](const float* buf, int t) {
        float ax = 0.f, ay = 0.f, az = 0.f, aw = 0.f;
        const float* Bp = buf + roff;
#pragma unroll
        for (int dy = 0; dy < 5; ++dy) {
            float2 lo = *(const float2*)(Bp + dy * HTW);       // cols -2,-1
            float4 md = *(const float4*)(Bp + dy * HTW + 2);   // cols 0..3
            float2 hi = *(const float2*)(Bp + dy * HTW + 6);   // cols 4,5
            const float a0 = lo.x, a1 = lo.y, a2 = md.x, a3 = md.y;
            const float a4 = md.z, a5 = md.w, a6 = hi.x, a7 = hi.y;
            const float k0 = kw[dy * 5 + 0], k1 = kw[dy * 5 + 1], k2 = kw[dy * 5 + 2];
            const float k3 = kw[dy * 5 + 3], k4 = kw[dy * 5 + 4];
            ax = fmaf(k0, a0, ax); ax = fmaf(k1, a1, ax);
            ax = fmaf(k2, a2, ax); ax = fmaf(k3, a3, ax);
            ax = fmaf(k4, a4, ax);
            ay = fmaf(k0, a1, ay); ay = fmaf(k1, a2, ay);
            ay = fmaf(k2, a3, ay); ay = fmaf(k3, a4, ay);
            ay = fmaf(k4, a5, ay);
            az = fmaf(k0, a2, az); az = fmaf(k1, a3, az);
            az = fmaf(k2, a4, az); az = fmaf(k3, a5, az);
            az = fmaf(k4, a6, az);
            aw = fmaf(k0, a3, aw); aw = fmaf(k1, a4, aw);
            aw = fmaf(k2, a5, aw); aw = fmaf(k3, a6, aw);
            aw = fmaf(k4, a7, aw);
        }
        // Non-temporal: the 256MB out stream must not evict halo-shared x in L2.
        __builtin_nontemporal_store(st, (vf4*)(out + (size_t)t * HW + obase));
        st.x = st.x - 0.2f * st.x + ax;                  // S_t = 0.8*S_{t-1} + y[t]
        st.y = st.y - 0.2f * st.y + ay;
        st.z = st.z - 0.2f * st.z + az;
        st.w = st.w - 0.2f * st.w + aw;
    };

    // Per step: [wait frame-t DMA] [reads+conv+store out[t]] [issue DMA t+3].
    // vmcnt count: after batch(t-3): store(t-2), 2 glds(t-2), store(t-1),
    // 2 glds(t-1) = 6 ops may remain outstanding.
#define ITER(T, B, W)                                                     \
    do {                                                                  \
        asm volatile("s_waitcnt vmcnt(%0)" ::"n"(W) : "memory");          \
        __builtin_amdgcn_sched_barrier(0);                                \
        STEP(&lds[B][0], (T));                                            \
        int tf_ = (T) + 3; if (tf_ > T_STEPS - 1) tf_ = T_STEPS - 1;      \
        GLDS(&lds[((B) + 3) & 3][0], tf_);                                \
    } while (0)

    // Prologue: frames 0..2 in flight.
    GLDS(&lds[0][0], 0);
    GLDS(&lds[1][0], 1);
    GLDS(&lds[2][0], 2);

    ITER(0, 0, 4);
    ITER(1, 1, 5);
    ITER(2, 2, 6);
    ITER(3, 3, 6);
#pragma clang loop unroll(disable)
    for (int tb = 4; tb < T_STEPS; tb += 4) {
        ITER(tb + 0, 0, 6);
        ITER(tb + 1, 1, 6);
        ITER(tb + 2, 2, 6);
        ITER(tb + 3, 3, 6);
    }
#undef ITER
}

extern "C" void kernel_launch(void* const* d_in, const int* in_sizes, int n_in,
                              void* d_out, int out_size, void* d_ws, size_t ws_size,
                              hipStream_t stream) {
    const float* x = (const float*)d_in[0];      // [256,1,512,512] f32
    const float* kern = (const float*)d_in[1];   // [5,5] f32
    float* out = (float*)d_out;                  // [256,1,512,512] f32

    conv_li_kernel<<<dim3(1024), dim3(64), 0, stream>>>(x, kern, out);
}

// Round 7
// 98.900 us; speedup vs baseline: 1.9592x; 1.9592x over previous
//
#include <hip/hip_runtime.h>

#define T_STEPS 256
#define IMG 512
#define HW (IMG * IMG)
#define TW 32
#define TH 8
#define HTW 40                 // dwords per halo row (cols -4..35) = 10 chunks
#define HTH 12                 // halo rows -2..9
#define NCHK 120               // real 16B chunks per frame
#define BUF_DW 512             // 128 chunks (8 dummy) * 4 dwords per frame buffer
#define NBUF 12                // ring of 12 frame buffers = 24 KiB LDS

// Zero page for fully-OOB halo chunks (device global: never written, stays 0).
__device__ __align__(16) float g_zeropage[8] = {0, 0, 0, 0, 0, 0, 0, 0};

typedef const __attribute__((address_space(1))) unsigned int* gptr_t;
typedef __attribute__((address_space(3))) unsigned int* lptr_t;
typedef float vf4 __attribute__((ext_vector_type(4)));

// out[t] = 0.8*out[t-1] + conv(x)[t-1]; out[0]=0 — conv and LI scan commute.
// Single-wave blocks, no barriers. global_load_lds staging, ring-12 buffers,
// groups of 4 steps per counted vmcnt (stores always newer than the waited
// glds batch -> never store-stalled). Reads are 3x aligned ds_read_b128
// covering the full bank lattice -> zero conflicts.
__launch_bounds__(64)
__global__ void conv_li_kernel(const float* __restrict__ x,
                               const float* __restrict__ kern,
                               float* __restrict__ out) {
    __shared__ __align__(16) float lds[NBUF][BUF_DW];
    const int tid = threadIdx.x;
    const int bid = blockIdx.x;
    // 1024 blocks over 8 XCDs (bijective): vertical halo sharing stays per-XCD L2.
    const int vbid = (bid & 7) * 128 + (bid >> 3);
    const int bx = vbid & 15;      // 16 tiles across
    const int by = vbid >> 4;      // 64 tile rows

    // 5x5 kernel -> wave-uniform (SGPR) weights.
    float kw[25];
#pragma unroll
    for (int i = 0; i < 25; ++i)
        kw[i] = __int_as_float(__builtin_amdgcn_readfirstlane(__float_as_int(kern[i])));

    // DMA source chunks: lane stages chunk tid (issue A) and tid+64 (issue B).
    // Chunk c -> halo row c/10, col-chunk c%10; every chunk is fully in-image
    // or fully out (-> zero page). gx is 16B-aligned.
    const float* srcA; const float* srcB; bool okA, okB;
    {
        int c = tid;
        int row = c / 10, cc = c - row * 10;
        int gy = by * TH + row - 2, gx = bx * TW + cc * 4 - 4;
        okA = (gy >= 0) && (gy < IMG) && (gx >= 0) && (gx <= IMG - 4);
        srcA = x + (size_t)(okA ? gy : 0) * IMG + (okA ? gx : 0);
        c = tid + 64;
        row = c / 10; cc = c - row * 10;
        gy = by * TH + row - 2; gx = bx * TW + cc * 4 - 4;
        okB = (c < NCHK) && (gy >= 0) && (gy < IMG) && (gx >= 0) && (gx <= IMG - 4);
        srcB = x + (size_t)(okB ? gy : 0) * IMG + (okB ? gx : 0);
    }

    auto GLDS = [&](int bi, int tf) {
        const float* pA = okA ? srcA + (size_t)tf * HW : g_zeropage;
        const float* pB = okB ? srcB + (size_t)tf * HW : g_zeropage;
        __builtin_amdgcn_global_load_lds((gptr_t)pA, (lptr_t)&lds[bi][0], 16, 0, 0);
        __builtin_amdgcn_global_load_lds((gptr_t)pB, (lptr_t)&lds[bi][256], 16, 0, 0);
    };
    auto BATCH = [&](int bufbase, int f0) {   // 4 frames = 8 glds, issued in order
#pragma unroll
        for (int j = 0; j < 4; ++j) {
            int tf = f0 + j; if (tf > T_STEPS - 1) tf = T_STEPS - 1;
            GLDS(bufbase + j, tf);
        }
    };

    const int q = tid & 7;         // col-quad (4 out cols)
    const int rr = tid >> 3;       // out row within tile
    const size_t obase = (size_t)(by * TH + rr) * IMG + bx * TW + q * 4;

    vf4 st = {0.f, 0.f, 0.f, 0.f};

    auto STEP = [&](int bi, int t) {
        float ax = 0.f, ay = 0.f, az = 0.f, aw = 0.f;
        // Row h = rr+dy starts at dword h*40; col (4q-4) at dword h*40+4q.
        // 3 aligned b128 -> elements e[i] = col 4q-4+i; conv uses e2..e9.
        const float* Bp = &lds[bi][rr * HTW + q * 4];
#pragma unroll
        for (int dy = 0; dy < 5; ++dy) {
            const float* L = Bp + dy * HTW;
            vf4 d0 = *(const vf4*)(L);
            vf4 d1 = *(const vf4*)(L + 4);
            vf4 d2 = *(const vf4*)(L + 8);
            const float e2 = d0.z, e3 = d0.w, e4 = d1.x, e5 = d1.y;
            const float e6 = d1.z, e7 = d1.w, e8 = d2.x, e9 = d2.y;
            const float k0 = kw[dy * 5 + 0], k1 = kw[dy * 5 + 1], k2 = kw[dy * 5 + 2];
            const float k3 = kw[dy * 5 + 3], k4 = kw[dy * 5 + 4];
            ax = fmaf(k0, e2, ax); ax = fmaf(k1, e3, ax); ax = fmaf(k2, e4, ax);
            ax = fmaf(k3, e5, ax); ax = fmaf(k4, e6, ax);
            ay = fmaf(k0, e3, ay); ay = fmaf(k1, e4, ay); ay = fmaf(k2, e5, ay);
            ay = fmaf(k3, e6, ay); ay = fmaf(k4, e7, ay);
            az = fmaf(k0, e4, az); az = fmaf(k1, e5, az); az = fmaf(k2, e6, az);
            az = fmaf(k3, e7, az); az = fmaf(k4, e8, az);
            aw = fmaf(k0, e5, aw); aw = fmaf(k1, e6, aw); aw = fmaf(k2, e7, aw);
            aw = fmaf(k3, e8, aw); aw = fmaf(k4, e9, aw);
        }
        vf4 s = st;
        __builtin_nontemporal_store(s, (vf4*)(out + (size_t)t * HW + obase));
        st.x = st.x - 0.2f * st.x + ax;      // S_t = 0.8*S_{t-1} + y[t]
        st.y = st.y - 0.2f * st.y + ay;
        st.z = st.z - 0.2f * st.z + az;
        st.w = st.w - 0.2f * st.w + aw;
    };

    // Prologue: frames 0..7 in flight (16 glds).
    BATCH(0, 0);
    BATCH(4, 4);

    // Group 0 (frames 0..3): outstanding 16, need oldest 8 -> vmcnt(8).
    asm volatile("s_waitcnt vmcnt(8)" ::: "memory");
    STEP(0, 0); STEP(1, 1); STEP(2, 2); STEP(3, 3);
    BATCH(8, 8);

    // Steady state: at group top, outstanding = batch(this:8) + stores(4) +
    // batch(next:8) = 20; waited batch is oldest -> vmcnt(12) never touches
    // stores. 21 super-groups x 12 steps = t 4..255.
#pragma clang loop unroll(disable)
    for (int sg = 0; sg < 21; ++sg) {
        const int t0 = 4 + sg * 12;
        asm volatile("s_waitcnt vmcnt(12)" ::: "memory");
        STEP(4, t0 + 0); STEP(5, t0 + 1); STEP(6, t0 + 2); STEP(7, t0 + 3);
        BATCH(0, t0 + 8);
        asm volatile("s_waitcnt vmcnt(12)" ::: "memory");
        STEP(8, t0 + 4); STEP(9, t0 + 5); STEP(10, t0 + 6); STEP(11, t0 + 7);
        BATCH(4, t0 + 12);
        asm volatile("s_waitcnt vmcnt(12)" ::: "memory");
        STEP(0, t0 + 8); STEP(1, t0 + 9); STEP(2, t0 + 10); STEP(3, t0 + 11);
        BATCH(8, t0 + 16);
    }
}

extern "C" void kernel_launch(void* const* d_in, const int* in_sizes, int n_in,
                              void* d_out, int out_size, void* d_ws, size_t ws_size,
                              hipStream_t stream) {
    const float* x = (const float*)d_in[0];      // [256,1,512,512] f32
    const float* kern = (const float*)d_in[1];   // [5,5] f32
    float* out = (float*)d_out;                  // [256,1,512,512] f32

    conv_li_kernel<<<dim3(1024), dim3(64), 0, stream>>>(x, kern, out);
}